// Round 7
// baseline (381.720 us; speedup 1.0000x reference)
//
#include <hip/hip_runtime.h>
#include <hip/hip_bf16.h>

// Problem constants (from reference): B=8, T=4096, E=16, H=64
#define BB 8
#define TT 4096
#define EE 16
#define HH 64
#define ZT 16      // colsum t-chunk split: 2048 blocks = 8/CU
#define NS 8       // out_mfma s-slice split: 2048 blocks = 8/CU

typedef __attribute__((ext_vector_type(8))) __bf16 bf16x8;  // MFMA A/B frag (4 VGPRs)
typedef __attribute__((ext_vector_type(4))) __bf16 bf16x4;  // packed 8B
typedef __attribute__((ext_vector_type(4))) float f32x4;    // MFMA C/D frag

// e^(d^(-1/16)): degree-4 poly in L=log2(d) (R13 coeffs, validated). 1 transc + 4 fma.
static __device__ __forceinline__ float exp_pow16(float d) {
    float L = __builtin_amdgcn_logf(d);            // v_log_f32 = log2
    float r = __builtin_fmaf(L, 2.72889e-6f, -1.536072e-4f);
    r = __builtin_fmaf(L, r, 4.946584e-3f);
    r = __builtin_fmaf(L, r, -0.11735442f);
    r = __builtin_fmaf(L, r, 2.71784054f);
    return r;
}

// ---- kernel 1: rank-16 factorization + zero Dsum/Z/counters ----------------
// S = Q K^T = x (Wq Wk^T) x^T — inner dim is E=16. Yb = bf16(x @ M),
// M = Wq Wk^T (per-block recompute, trivial), xb = bf16(x).
__global__ __launch_bounds__(256) void proj_kernel(
        const float* __restrict__ x, const float* __restrict__ Wq,
        const float* __restrict__ Wk,
        __bf16* __restrict__ Yb, __bf16* __restrict__ xb,
        float* __restrict__ Dsum, float* __restrict__ Z,
        int* __restrict__ cnt) {
    __shared__ float Ms[16][16];
    __shared__ float xs[16][16];
    int tid = threadIdx.x;
    size_t gid = (size_t)blockIdx.x * 256 + tid;
    // zero Dsum (8192 float4) and Z (131072 float4) before consumers (stream order)
    if (gid < (size_t)BB * TT / 4)
        ((float4*)Dsum)[gid] = (float4){0.f, 0.f, 0.f, 0.f};
    if (gid < (size_t)BB * TT * EE / 4)
        ((float4*)Z)[gid] = (float4){0.f, 0.f, 0.f, 0.f};
    // zero completion counters (128 for colsum + 256 for out)
    if (blockIdx.x == 0)
        for (int i = tid; i < 384; i += 256) cnt[i] = 0;
    int i = tid >> 4, j = tid & 15;
    float m = 0.f;
#pragma unroll 8
    for (int h = 0; h < HH; ++h) m += Wq[i * HH + h] * Wk[j * HH + h];
    Ms[i][j] = m;
    int row0 = blockIdx.x * 16;
    xs[i][j] = x[(size_t)(row0 + i) * EE + j];   // 256 consecutive floats
    __syncthreads();
    float y = 0.f;
#pragma unroll
    for (int k = 0; k < EE; ++k) y += xs[i][k] * Ms[k][j];
    size_t idx = (size_t)(row0 + i) * EE + j;
    Yb[idx] = (__bf16)y;
    xb[idx] = (__bf16)xs[i][j];
}

// ---- kernel 2: Dsum[b][s] += sum_{t in chunk z} exp((Y_t·x_s)^(-1/16)) -----
// R14 structure (zero-LDS main loop, register prefetch, unconditional streamed
// loads). R15: (a) poly constant term hoisted out of the loop — last fma
// doubles as the accumulator, +256*c0 added once per s at the end; (b) last
// arriving block per (b, s-block) builds xDT inline (xd_kernel folded in).
__global__ __launch_bounds__(256) void colsum_mfma(
        const __bf16* __restrict__ Yb, const __bf16* __restrict__ xb,
        float* __restrict__ Dsum, __bf16* __restrict__ xDT,
        int* __restrict__ cnt1) {
    __shared__ int isLast;
    int lane = threadIdx.x & 63;
    int w = threadIdx.x >> 6;
    int quad = lane >> 4;
    int l15 = lane & 15;
    int b = blockIdx.y;
    int z = blockIdx.z;
    int s0 = blockIdx.x * 256 + w * 64;

    const __bf16* xbb = xb + (size_t)b * TT * EE;
    const __bf16* Ybb = Yb + (size_t)b * TT * EE;

    // B[k=e][n=s]: lane holds xb[s0+st*16+l15][quad*8..+7]; k>=16 zero-padded
    bf16x8 bx[4];
#pragma unroll
    for (int st = 0; st < 4; ++st) {
        bf16x8 v = {};
        if (quad < 2)
            v = *(const bf16x8*)(xbb + (size_t)(s0 + st * 16 + l15) * EE + quad * 8);
        bx[st] = v;
    }

    // streamed A base: unconditional, quads 2-3 alias quads 0-1's bytes
    const __bf16* gya = Ybb + (size_t)l15 * EE + (quad & 1) * 8;

    const int TL = TT / ZT;                  // 256 t per block
    int t0 = z * TL, tend = t0 + TL;

    float csum[4] = {0.f, 0.f, 0.f, 0.f};

    auto LOADY = [&](bf16x8 ya[2], int t) {  // A[m=t][k=e]
#pragma unroll
        for (int ts = 0; ts < 2; ++ts)
            ya[ts] = *(const bf16x8*)(gya + (size_t)(t + ts * 16) * EE);
    };
    auto BODY = [&](bf16x8 ya[2]) {
#pragma unroll
        for (int st = 0; st < 4; ++st) {
#pragma unroll
            for (int ts = 0; ts < 2; ++ts) {
                f32x4 c = {0.f, 0.f, 0.f, 0.f};
                c = __builtin_amdgcn_mfma_f32_16x16x32_bf16(ya[ts], bx[st], c, 0, 0, 0);
#pragma unroll
                for (int r = 0; r < 4; ++r) {
                    // poly minus constant; fma folds the accumulate
                    float L = __builtin_amdgcn_logf(c[r]);
                    float p = __builtin_fmaf(L, 2.72889e-6f, -1.536072e-4f);
                    p = __builtin_fmaf(L, p, 4.946584e-3f);
                    p = __builtin_fmaf(L, p, -0.11735442f);
                    csum[st] = __builtin_fmaf(L, p, csum[st]);
                }
            }
        }
    };

    bf16x8 yaA[2], yaB[2];
    LOADY(yaA, t0);
    for (int t = t0; t < tend; t += 64) {     // TL % 64 == 0
        LOADY(yaB, t + 32);
        BODY(yaA);
        int tn = (t + 64 < tend) ? (t + 64) : t0;   // last: dummy reload
        LOADY(yaA, tn);
        BODY(yaB);
    }

    // C: row=t=quad*4+r (summed in-reg + cross-quad shuffle), col=s=l15.
    // 256 elements contributed per (s, block): add back 256 * poly-const.
#pragma unroll
    for (int st = 0; st < 4; ++st) {
        float r = csum[st];
        r += __shfl_xor(r, 16, 64);
        r += __shfl_xor(r, 32, 64);
        if (quad == 0)
            atomicAdd(&Dsum[(size_t)b * TT + s0 + st * 16 + l15],
                      r + 256.0f * 2.71784054f);
    }

    // ---- folded xd epilogue: last block per (b, s-block of 256) ------------
    __syncthreads();                          // all waves' atomics drained
    __threadfence();                          // order before counter bump
    if (threadIdx.x == 0) {
        int old = atomicAdd(&cnt1[b * (TT / 256) + blockIdx.x], 1);
        isLast = (old == ZT - 1);
    }
    __syncthreads();
    if (!isLast) return;

    int tid = threadIdx.x;
    int s = blockIdx.x * 256 + tid;           // 256 threads = 256 s
    // coherent read of the fully-accumulated Dsum (other blocks wrote via atomics)
    float d = atomicAdd(&Dsum[(size_t)b * TT + s], 0.0f);
    float rv = 1.0f / d;
    const __bf16* xr = xbb + (size_t)s * EE;
    bf16x8 x0 = *(const bf16x8*)xr;
    bf16x8 x1 = *(const bf16x8*)(xr + 8);
    __bf16* xdp = xDT + (size_t)b * EE * TT + s;
#pragma unroll
    for (int e = 0; e < 8; ++e)
        xdp[(size_t)e * TT] = (__bf16)((float)x0[e] * rv);      // coalesced per e
#pragma unroll
    for (int e = 0; e < 8; ++e)
        xdp[(size_t)(e + 8) * TT] = (__bf16)((float)x1[e] * rv);
}

// ---- kernel 3: Z[b][t][e] += sum_{s in slice z} exp(S_ts) * xDT[e][s] ------
// R14 structure (2-tiles/wave, Etile double-buffer 1-stage-lag, zero barriers
// in the main loop). R15: last block per (b, t-block of 128) applies the
// tiny x Wk epilogue inline (zout_kernel folded in), reusing Etile's LDS.
__global__ __launch_bounds__(256) void out_mfma(
        const __bf16* __restrict__ Yb, const __bf16* __restrict__ xb,
        const __bf16* __restrict__ xDT, float* __restrict__ Z,
        const float* __restrict__ Wk, float* __restrict__ out,
        int* __restrict__ cnt2) {
    __shared__ __bf16 Etile[2][4][2][16 * 40]; // [buf][wave][tile] E[t16][s32 pad8]
    __shared__ int isLast;

    int lane = threadIdx.x & 63;
    int w = threadIdx.x >> 6;
    int quad = lane >> 4;
    int l15 = lane & 15;
    int b = blockIdx.y;
    int z = blockIdx.z;
    int t0 = blockIdx.x * 128 + w * 32;      // wave owns TWO 16-t tiles

    const __bf16* xbb = xb + (size_t)b * TT * EE;
    const __bf16* Ybb = Yb + (size_t)b * TT * EE;
    const __bf16* xdb = xDT + (size_t)b * EE * TT;

    // persistent B of S^T: B[k=e][n=t] = Y[t0+tile*16+l15][quad*8..]; zero k>=16
    bf16x8 yf[2];
#pragma unroll
    for (int tile = 0; tile < 2; ++tile) {
        bf16x8 v = {};
        if (quad < 2)
            v = *(const bf16x8*)(Ybb + (size_t)(t0 + tile * 16 + l15) * EE + quad * 8);
        yf[tile] = v;
    }

    f32x4 acc[2] = {{0.f, 0.f, 0.f, 0.f}, {0.f, 0.f, 0.f, 0.f}};

    // streamed A base (unconditional; quads 2-3 alias quads 0-1 bytes, x0 by yf)
    const __bf16* gaf = xbb + (size_t)l15 * EE + (quad & 1) * 8;
    // PV B base: B[k=s_loc=quad*8+j][n=e=l15] = xDT[e=l15][s+quad*8..+7]
    const __bf16* gxd = xdb + (size_t)l15 * TT + quad * 8;

    const int SL = TT / NS;                  // 512 s -> 16 stages of 32 s
    int s0z = z * SL, send = s0z + SL;

    auto LOADF = [&](bf16x8 af[2], bf16x8& bxd, int s) {
#pragma unroll
        for (int ss = 0; ss < 2; ++ss)
            af[ss] = *(const bf16x8*)(gaf + (size_t)(s + ss * 16) * EE);
        bxd = *(const bf16x8*)(gxd + s);
    };
    auto STAGE = [&](bf16x8 af[2], int p) {  // QK + exp -> Etile[p]
#pragma unroll
        for (int tile = 0; tile < 2; ++tile) {
#pragma unroll
            for (int ss = 0; ss < 2; ++ss) {
                // S^T: row = s_loc = ss*16+quad*4+r, col = t_loc = l15
                f32x4 c = {0.f, 0.f, 0.f, 0.f};
                c = __builtin_amdgcn_mfma_f32_16x16x32_bf16(af[ss], yf[tile], c, 0, 0, 0);
                bf16x4 e;
#pragma unroll
                for (int r = 0; r < 4; ++r)
                    e[r] = (__bf16)exp_pow16(c[r]);
                // E[t=l15][s = ss*16 + quad*4 .. +3]: one packed 8B write
                *(bf16x4*)&Etile[p][w][tile][l15 * 40 + ss * 16 + quad * 4] = e;
            }
        }
    };
    auto PV = [&](bf16x8& bxd, int p) {
#pragma unroll
        for (int tile = 0; tile < 2; ++tile) {
            // A[m=t=l15][k=s=quad*8+j] from Etile[p] — contiguous b128
            bf16x8 aE = *(const bf16x8*)&Etile[p][w][tile][l15 * 40 + quad * 8];
            acc[tile] = __builtin_amdgcn_mfma_f32_16x16x32_bf16(aE, bxd, acc[tile], 0, 0, 0);
        }
    };

    bf16x8 afA[2], afB[2], bxdA, bxdB;
    LOADF(afA, bxdA, s0z);
    STAGE(afA, 0);                           // stage 0 -> buf 0
    for (int s = s0z; s < send; s += 64) {   // SL % 64 == 0
        LOADF(afB, bxdB, s + 32);
        STAGE(afB, 1);                       // stage i+1 -> buf 1
        PV(bxdA, 0);                         // consume stage i
        int sn = s + 64;
        if (sn < send) {
            LOADF(afA, bxdA, sn);
            STAGE(afA, 0);
        }
        PV(bxdB, 1);
    }

    // Z[t][e]: row = t0 + tile*16 + quad*4 + r, col = e = l15 (NS contrib/addr)
    float* zp = Z + ((size_t)b * TT + t0) * EE;
#pragma unroll
    for (int tile = 0; tile < 2; ++tile)
#pragma unroll
        for (int r = 0; r < 4; ++r)
            atomicAdd(&zp[(size_t)(tile * 16 + quad * 4 + r) * EE + l15], acc[tile][r]);

    // ---- folded zout epilogue: last block per (b, t-block of 128) ----------
    __syncthreads();                          // all waves' atomics drained
    __threadfence();
    if (threadIdx.x == 0) {
        int old = atomicAdd(&cnt2[b * (TT / 128) + blockIdx.x], 1);
        isLast = (old == NS - 1);
    }
    __syncthreads();
    if (!isLast) return;

    int tid = threadIdx.x;
    int t0b = blockIdx.x * 128;
    float* zs = (float*)&Etile[0][0][0][0];   // reuse 20KB LDS (>= 8KB needed)
    float* Zbase = Z + ((size_t)b * TT + t0b) * EE;
#pragma unroll
    for (int i = tid; i < 128 * 16; i += 256)
        zs[i] = atomicAdd(&Zbase[i], 0.0f);   // coherent read of accumulated Z
    __syncthreads();
    int h = tid & 63, tg = tid >> 6;
    float wcol[16];
#pragma unroll
    for (int e = 0; e < EE; ++e) wcol[e] = Wk[e * HH + h];
    float* ob = out + ((size_t)b * TT + t0b) * HH + h;
#pragma unroll
    for (int k = 0; k < 32; ++k) {
        int tl = tg * 32 + k;
        float o = 0.f;
#pragma unroll
        for (int e = 0; e < EE; ++e)
            o = __builtin_fmaf(zs[tl * 16 + e], wcol[e], o);  // LDS broadcast
        ob[(size_t)tl * HH] = o;              // coalesced across h
    }
}

extern "C" void kernel_launch(void* const* d_in, const int* in_sizes, int n_in,
                              void* d_out, int out_size, void* d_ws, size_t ws_size,
                              hipStream_t stream) {
    const float* x  = (const float*)d_in[0];
    const float* Wq = (const float*)d_in[1];
    const float* Wk = (const float*)d_in[2];
    // d_in[3] (Wv) unused: reference computes v = x @ Wk (faithful quirk).

    const size_t NE16 = (size_t)BB * TT * EE;    // 524288
    char* wp = (char*)d_ws;
    __bf16* Yb   = (__bf16*)wp;  wp += NE16 * 2;              // 1 MB
    __bf16* xbb  = (__bf16*)wp;  wp += NE16 * 2;              // 1 MB
    __bf16* xDT  = (__bf16*)wp;  wp += NE16 * 2;              // 1 MB
    float*  Dsum = (float*)wp;   wp += (size_t)BB * TT * 4;   // 128 KB
    float*  Zws  = (float*)wp;   wp += NE16 * 4;              // 2 MB
    int*    cnt  = (int*)wp;                                  // 384 ints
    int*    cnt1 = cnt;                                       // 128
    int*    cnt2 = cnt + 128;                                 // 256

    float* out = (float*)d_out;

    proj_kernel<<<BB * TT / 16, 256, 0, stream>>>(x, Wq, Wk, Yb, xbb, Dsum, Zws, cnt);
    colsum_mfma<<<dim3(TT / 256, BB, ZT), 256, 0, stream>>>(Yb, xbb, Dsum, xDT, cnt1);
    out_mfma<<<dim3(TT / 128, BB, NS), 256, 0, stream>>>(Yb, xbb, xDT, Zws, Wk, out, cnt2);
}

// Round 8
// 141.383 us; speedup vs baseline: 2.6999x; 2.6999x over previous
//
#include <hip/hip_runtime.h>
#include <hip/hip_bf16.h>

// Problem constants (from reference): B=8, T=4096, E=16, H=64
#define BB 8
#define TT 4096
#define EE 16
#define HH 64
#define ZT 16      // colsum t-chunk split: 2048 blocks = 8/CU
#define NS 8       // out_mfma s-slice split: 2048 blocks = 8/CU

typedef __attribute__((ext_vector_type(8))) __bf16 bf16x8;   // MFMA A/B frag (4 VGPRs)
typedef __attribute__((ext_vector_type(4))) __bf16 bf16x4;   // packed 8B
typedef __attribute__((ext_vector_type(4))) float f32x4;     // 16x16 C/D frag
typedef __attribute__((ext_vector_type(16))) float f32x16;   // 32x32 C/D frag

// e^(d^(-1/16)): degree-4 poly in L=log2(d) (R13 coeffs, validated). 1 transc + 4 fma.
static __device__ __forceinline__ float exp_pow16(float d) {
    float L = __builtin_amdgcn_logf(d);            // v_log_f32 = log2
    float r = __builtin_fmaf(L, 2.72889e-6f, -1.536072e-4f);
    r = __builtin_fmaf(L, r, 4.946584e-3f);
    r = __builtin_fmaf(L, r, -0.11735442f);
    r = __builtin_fmaf(L, r, 2.71784054f);
    return r;
}

// ---- kernel 1: rank-16 factorization (R11) + zero Dsum ---------------------
// S = Q K^T = x (Wq Wk^T) x^T — inner dim is E=16. Yb = bf16(x @ M),
// M = Wq Wk^T (per-block recompute, trivial), xb = bf16(x).
__global__ __launch_bounds__(256) void proj_kernel(
        const float* __restrict__ x, const float* __restrict__ Wq,
        const float* __restrict__ Wk,
        __bf16* __restrict__ Yb, __bf16* __restrict__ xb,
        float* __restrict__ Dsum) {
    __shared__ float Ms[16][16];
    __shared__ float xs[16][16];
    int tid = threadIdx.x;
    // zero Dsum (B*T floats = 8192 float4) before colsum (stream-ordered)
    size_t gid = (size_t)blockIdx.x * 256 + tid;
    if (gid < (size_t)BB * TT / 4)
        ((float4*)Dsum)[gid] = (float4){0.f, 0.f, 0.f, 0.f};
    int i = tid >> 4, j = tid & 15;
    float m = 0.f;
#pragma unroll 8
    for (int h = 0; h < HH; ++h) m += Wq[i * HH + h] * Wk[j * HH + h];
    Ms[i][j] = m;
    int row0 = blockIdx.x * 16;
    xs[i][j] = x[(size_t)(row0 + i) * EE + j];   // 256 consecutive floats
    __syncthreads();
    float y = 0.f;
#pragma unroll
    for (int k = 0; k < EE; ++k) y += xs[i][k] * Ms[k][j];
    size_t idx = (size_t)(row0 + i) * EE + j;
    Yb[idx] = (__bf16)y;
    xb[idx] = (__bf16)xs[i][j];
}

// ---- kernel 2: Dsum[b][s] += sum_{t in chunk z} exp((Y_t·x_s)^(-1/16)) -----
// R16: 32x32x16 MFMA — K=16 matches E exactly (no zero-pad half). Per 32-t
// stage: 2 MFMA (was 8) + one 16B streamed Y frag (was 2). C layout (verified
// m74/m101): col = lane&31 = s, row = (r&3)+8*(r>>2)+4*(lane>>5) = t; the 16
// regs + hi/lo halves cover all 32 t. Poly constant hoisted: last fma is the
// accumulator, +256*c0 once per s at the end.
__global__ __launch_bounds__(256) void colsum_mfma(
        const __bf16* __restrict__ Yb, const __bf16* __restrict__ xb,
        float* __restrict__ Dsum) {
    int lane = threadIdx.x & 63;
    int w = threadIdx.x >> 6;
    int wl = lane & 31;
    int hi = lane >> 5;
    int b = blockIdx.y;
    int z = blockIdx.z;
    int s0 = blockIdx.x * 256 + w * 64;      // wave owns 64 s = 2 x 32-s groups

    const __bf16* xbb = xb + (size_t)b * TT * EE;
    const __bf16* Ybb = Yb + (size_t)b * TT * EE;

    // persistent B[k=e][n=s]: lane holds xb[s0+sg*32+wl][hi*8..+7] (16B, no pad)
    bf16x8 bx[2];
#pragma unroll
    for (int sg = 0; sg < 2; ++sg)
        bx[sg] = *(const bf16x8*)(xbb + (size_t)(s0 + sg * 32 + wl) * EE + hi * 8);

    // streamed A[m=t][k=e] base: lane reads Y[t+wl][hi*8..+7] (16B)
    const __bf16* gya = Ybb + (size_t)wl * EE + hi * 8;

    const int TL = TT / ZT;                  // 256 t per block -> 8 stages of 32
    int t0 = z * TL, tend = t0 + TL;

    float csum[2] = {0.f, 0.f};

    auto BODY = [&](bf16x8 ya) {
#pragma unroll
        for (int sg = 0; sg < 2; ++sg) {
            f32x16 c = {};
            c = __builtin_amdgcn_mfma_f32_32x32x16_bf16(ya, bx[sg], c, 0, 0, 0);
#pragma unroll
            for (int r = 0; r < 16; ++r) {
                // poly minus constant; fma folds the accumulate
                float L = __builtin_amdgcn_logf(c[r]);
                float p = __builtin_fmaf(L, 2.72889e-6f, -1.536072e-4f);
                p = __builtin_fmaf(L, p, 4.946584e-3f);
                p = __builtin_fmaf(L, p, -0.11735442f);
                csum[sg] = __builtin_fmaf(L, p, csum[sg]);
            }
        }
    };

    bf16x8 yaA, yaB;
    yaA = *(const bf16x8*)(gya + (size_t)t0 * EE);
    for (int t = t0; t < tend; t += 64) {     // TL % 64 == 0
        yaB = *(const bf16x8*)(gya + (size_t)(t + 32) * EE);
        BODY(yaA);
        int tn = (t + 64 < tend) ? (t + 64) : t0;   // last: dummy reload
        yaA = *(const bf16x8*)(gya + (size_t)tn * EE);
        BODY(yaB);
    }

    // csum[sg]: sum over this lane's 16 t-rows; + other half via xor-32.
    // 256 t contributed per (s, block): add back 256 * poly-const.
#pragma unroll
    for (int sg = 0; sg < 2; ++sg) {
        float r = csum[sg];
        r += __shfl_xor(r, 32, 64);
        if (lane < 32)
            atomicAdd(&Dsum[(size_t)b * TT + s0 + sg * 32 + wl],
                      r + 256.0f * 2.71784054f);
    }
}

// ---- kernel 3: xDT[b][e][s] = bf16(x[s][e] / Dsum[b][s]); zero Z -----------
__global__ __launch_bounds__(256) void xd_kernel(
        const __bf16* __restrict__ xb, const float* __restrict__ Dsum,
        __bf16* __restrict__ xDT, float* __restrict__ Z) {
    __shared__ float Rs[64];
    __shared__ __bf16 tt[16][68];
    int b = blockIdx.y;
    int s0 = blockIdx.x * 64;
    int tid = threadIdx.x;
    // zero Z (B*T*16 floats = 131072 float4 == grid total threads exactly)
    size_t zi = ((size_t)b * gridDim.x + blockIdx.x) * 256 + tid;
    ((float4*)Z)[zi] = (float4){0.f, 0.f, 0.f, 0.f};
    if (tid < 64)
        Rs[tid] = 1.0f / Dsum[(size_t)b * TT + s0 + tid];   // coalesced
    __syncthreads();
    int sl = tid & 63, eg = tid >> 6;        // e-range eg*4..+3
    bf16x4 v = *(const bf16x4*)(xb + ((size_t)b * TT + s0 + sl) * EE + eg * 4);
    float r = Rs[sl];
#pragma unroll
    for (int i = 0; i < 4; ++i) tt[eg * 4 + i][sl] = (__bf16)((float)v[i] * r);
    __syncthreads();
    int e = tid >> 4, sc = tid & 15;
    *(bf16x4*)(xDT + ((size_t)b * EE + e) * TT + s0 + sc * 4) = *(const bf16x4*)&tt[e][sc * 4];
}

// ---- kernel 4: Z[b][t][e] += sum_{s in slice z} exp(S_ts) * xDT[e][s] ------
// R16: QK via ONE 32x32x16 MFMA per 32-s stage (was 4 padded 16x16x32):
// S^T with A=xb (m=s), B=Y (n=t): C col = t = lane&31, row = s =
// (r&3)+8*(r>>2)+4*hi. Reg quartets are 4 consecutive s -> 4 packed
// ds_write_b64 per stage into E[t][s] (row stride 36 bf16: <=2-way banks).
// PV unchanged (2 x 16x16x32 over t-halves). R14's 1-stage-lag Etile double
// buffer and register prefetch kept; zero barriers (wave-private Etile).
__global__ __launch_bounds__(256) void out_mfma(
        const __bf16* __restrict__ Yb, const __bf16* __restrict__ xb,
        const __bf16* __restrict__ xDT, float* __restrict__ Z) {
    __shared__ __bf16 Etile[2][4][32 * 36]; // [buf][wave] E[t 32][s 32 pad4]

    int lane = threadIdx.x & 63;
    int w = threadIdx.x >> 6;
    int wl = lane & 31;
    int hi = lane >> 5;
    int quad = lane >> 4;                    // for PV (16x16 frags)
    int l15 = lane & 15;
    int b = blockIdx.y;
    int z = blockIdx.z;
    int t0 = blockIdx.x * 128 + w * 32;      // wave owns one 32-t tile

    const __bf16* xbb = xb + (size_t)b * TT * EE;
    const __bf16* Ybb = Yb + (size_t)b * TT * EE;
    const __bf16* xdb = xDT + (size_t)b * EE * TT;

    // persistent B of S^T: B[k=e][n=t]: lane holds Y[t0+wl][hi*8..+7] (no pad)
    bf16x8 yf = *(const bf16x8*)(Ybb + (size_t)(t0 + wl) * EE + hi * 8);

    f32x4 acc[2] = {{0.f, 0.f, 0.f, 0.f}, {0.f, 0.f, 0.f, 0.f}};

    // streamed A of S^T: xb[s+wl][hi*8..+7] (16B)
    const __bf16* gaf = xbb + (size_t)wl * EE + hi * 8;
    // PV B: B[k=s_loc=quad*8+j][n=e=l15] = xDT[e=l15][s+quad*8..+7]
    const __bf16* gxd = xdb + (size_t)l15 * TT + quad * 8;

    const int SL = TT / NS;                  // 512 s -> 16 stages of 32 s
    int s0z = z * SL, send = s0z + SL;

    auto STAGE = [&](bf16x8 af, int p) {     // QK + exp -> Etile[p]
        f32x16 c = {};
        c = __builtin_amdgcn_mfma_f32_32x32x16_bf16(af, yf, c, 0, 0, 0);
        // E[t=wl][s = 8*g + 4*hi .. +3] from reg quartet g
#pragma unroll
        for (int g = 0; g < 4; ++g) {
            bf16x4 e;
#pragma unroll
            for (int r = 0; r < 4; ++r)
                e[r] = (__bf16)exp_pow16(c[g * 4 + r]);
            *(bf16x4*)&Etile[p][w][wl * 36 + g * 8 + hi * 4] = e;
        }
    };
    auto PV = [&](bf16x8& bxd, int p) {
#pragma unroll
        for (int h2 = 0; h2 < 2; ++h2) {
            // A[m=t=h2*16+l15][k=s=quad*8+j] from Etile[p] — contiguous b128
            bf16x8 aE = *(const bf16x8*)&Etile[p][w][(h2 * 16 + l15) * 36 + quad * 8];
            acc[h2] = __builtin_amdgcn_mfma_f32_16x16x32_bf16(aE, bxd, acc[h2], 0, 0, 0);
        }
    };

    bf16x8 afA, afB, bxdA, bxdB;
    afA = *(const bf16x8*)(gaf + (size_t)s0z * EE);
    bxdA = *(const bf16x8*)(gxd + s0z);
    STAGE(afA, 0);                           // stage 0 -> buf 0
    for (int s = s0z; s < send; s += 64) {   // SL % 64 == 0
        afB = *(const bf16x8*)(gaf + (size_t)(s + 32) * EE);
        bxdB = *(const bf16x8*)(gxd + (s + 32));
        STAGE(afB, 1);                       // stage i+1 -> buf 1
        PV(bxdA, 0);                         // consume stage i
        int sn = s + 64;
        if (sn < send) {
            afA = *(const bf16x8*)(gaf + (size_t)sn * EE);
            bxdA = *(const bf16x8*)(gxd + sn);
            STAGE(afA, 0);
        }
        PV(bxdB, 1);
    }

    // Z[t][e]: t = t0 + h2*16 + quad*4 + r, e = l15 (NS contributions/address)
    float* zp = Z + ((size_t)b * TT + t0) * EE;
#pragma unroll
    for (int h2 = 0; h2 < 2; ++h2)
#pragma unroll
        for (int r = 0; r < 4; ++r)
            atomicAdd(&zp[(size_t)(h2 * 16 + quad * 4 + r) * EE + l15], acc[h2][r]);
}

// ---- kernel 5: out[b][t][h] = Z[b][t][:] @ Wk ------------------------------
// Fully coalesced: float4 Z loads (2MB total), LDS broadcast reads,
// per-thread Wk column in registers, coalesced out writes.
__global__ __launch_bounds__(256) void zout_kernel(
        const float* __restrict__ Z, const float* __restrict__ Wk,
        float* __restrict__ out) {
    __shared__ float zs[64][16];             // 64 t-rows x 16 e (flat-filled)
    int b = blockIdx.y;
    int t0 = blockIdx.x * 64;
    int tid = threadIdx.x;
    ((float4*)zs)[tid] = ((const float4*)(Z + ((size_t)b * TT + t0) * EE))[tid];
    __syncthreads();
    int h = tid & 63, tg = tid >> 6;
    float wcol[16];
#pragma unroll
    for (int e = 0; e < EE; ++e) wcol[e] = Wk[e * HH + h];
    float* ob = out + ((size_t)b * TT + t0) * HH + h;
#pragma unroll
    for (int k = 0; k < 16; ++k) {
        int tl = tg * 16 + k;
        float o = 0.f;
#pragma unroll
        for (int e = 0; e < EE; ++e) o = __builtin_fmaf(zs[tl][e], wcol[e], o);
        ob[(size_t)tl * HH] = o;             // all lanes read same zs row: broadcast
    }
}

extern "C" void kernel_launch(void* const* d_in, const int* in_sizes, int n_in,
                              void* d_out, int out_size, void* d_ws, size_t ws_size,
                              hipStream_t stream) {
    const float* x  = (const float*)d_in[0];
    const float* Wq = (const float*)d_in[1];
    const float* Wk = (const float*)d_in[2];
    // d_in[3] (Wv) unused: reference computes v = x @ Wk (faithful quirk).

    const size_t NE16 = (size_t)BB * TT * EE;    // 524288
    char* wp = (char*)d_ws;
    __bf16* Yb   = (__bf16*)wp;  wp += NE16 * 2;              // 1 MB
    __bf16* xbb  = (__bf16*)wp;  wp += NE16 * 2;              // 1 MB
    __bf16* xDT  = (__bf16*)wp;  wp += NE16 * 2;              // 1 MB
    float*  Dsum = (float*)wp;   wp += (size_t)BB * TT * 4;   // 128 KB
    float*  Zws  = (float*)wp;                                // 2 MB

    float* out = (float*)d_out;

    proj_kernel<<<BB * TT / 16, 256, 0, stream>>>(x, Wq, Wk, Yb, xbb, Dsum);
    colsum_mfma<<<dim3(TT / 256, BB, ZT), 256, 0, stream>>>(Yb, xbb, Dsum);
    xd_kernel<<<dim3(TT / 64, BB), 256, 0, stream>>>(xbb, Dsum, xDT, Zws);
    out_mfma<<<dim3(TT / 128, BB, NS), 256, 0, stream>>>(Yb, xbb, xDT, Zws);
    zout_kernel<<<dim3(TT / 64, BB), 256, 0, stream>>>(Zws, Wk, out);
}